// Round 3
// baseline (9199.896 us; speedup 1.0000x reference)
//
#include <hip/hip_runtime.h>
#include <math.h>

#define B_   32
#define L_   1024
#define C_   32
#define D_   512
#define SEG_ 16
#define SX_  64
#define N_   1024   // B*C

typedef _Float16 f16x8 __attribute__((ext_vector_type(8)));
typedef float    f32x4 __attribute__((ext_vector_type(4)));

__device__ __forceinline__ void stage16(const void* g, void* l) {
    __builtin_amdgcn_global_load_lds((const __attribute__((address_space(1))) void*)g,
                                     (__attribute__((address_space(3))) void*)l, 16, 0, 0);
}

// ---------------------------------------------------------------------------
// prep: x (B,L,C) -> xs_seg, xt_seg fp32 (step, n, seg); channel-axis moving
// mean (reference semantics), window 25, edge replication.
// ---------------------------------------------------------------------------
__global__ __launch_bounds__(256) void prep_kernel(const float* __restrict__ x,
                                                   float* __restrict__ xs_seg,
                                                   float* __restrict__ xt_seg) {
    int b = blockIdx.x >> 2;
    int t = ((blockIdx.x & 3) << 8) + threadIdx.x;
    const float* xb    = x + (size_t)b * (L_ * C_);
    const float* xrow  = xb + (size_t)t * C_;
    const float* xlast = xb + (size_t)(L_ - 1) * C_;

    float diff[C_];
#pragma unroll
    for (int c = 0; c < C_; ++c) diff[c] = xrow[c] - xlast[c];
    float ps[C_ + 1];
    ps[0] = 0.f;
#pragma unroll
    for (int c = 0; c < C_; ++c) ps[c + 1] = ps[c] + diff[c];

    int s = t >> 4, q = t & 15;
#pragma unroll
    for (int c = 0; c < C_; ++c) {
        int lo = c - 12, hi = c + 12;
        float sum = ps[(hi < 31 ? hi : 31) + 1] - ps[lo > 0 ? lo : 0];
        if (lo < 0)  sum += (float)(-lo)     * diff[0];
        if (hi > 31) sum += (float)(hi - 31) * diff[31];
        float mean = sum * (1.0f / 25.0f);
        size_t idx = ((size_t)s * N_ + (size_t)(b * C_ + c)) * SEG_ + q;
        xt_seg[idx] = mean;
        xs_seg[idx] = diff[c] - mean;
    }
}

// ---------------------------------------------------------------------------
// emb batch: emb_buf[sl][gru][n][512] f16 = relu(xseg @ W_emb^T + b_emb)
// ---------------------------------------------------------------------------
__global__ __launch_bounds__(256) void emb_kernel(
    const float* __restrict__ xs_seg, const float* __restrict__ xt_seg,
    const float* __restrict__ W_emb, const float* __restrict__ b_emb,
    _Float16* __restrict__ emb_buf, int s0) {
    int bid = blockIdx.x;
    int gru = bid >> 8, sl = (bid >> 4) & 15, nch = bid & 15;
    int step = s0 + sl, n0 = nch * 64;
    const float* xseg = gru ? xt_seg : xs_seg;
    __shared__ float xl[64 * 16];
    int tid = threadIdx.x;
    const float* src = xseg + ((size_t)step * N_ + n0) * SEG_;
    for (int i = tid; i < 1024; i += 256) xl[i] = src[i];
    float w1[16], w2[16];
#pragma unroll
    for (int q = 0; q < 16; ++q) {
        w1[q] = W_emb[tid * 16 + q];
        w2[q] = W_emb[(tid + 256) * 16 + q];
    }
    float b1 = b_emb[tid], b2 = b_emb[tid + 256];
    __syncthreads();
    _Float16* dst = emb_buf + ((size_t)(sl * 2 + gru) * N_ + n0) * D_;
    for (int r = 0; r < 64; ++r) {
        float a1 = b1, a2 = b2;
#pragma unroll
        for (int q = 0; q < 16; ++q) {
            float xv = xl[r * 16 + q];
            a1 = fmaf(xv, w1[q], a1);
            a2 = fmaf(xv, w2[q], a2);
        }
        a1 = a1 > 0.f ? a1 : 0.f;
        a2 = a2 > 0.f ? a2 : 0.f;
        dst[(size_t)r * D_ + tid]       = (_Float16)a1;
        dst[(size_t)r * D_ + tid + 256] = (_Float16)a2;
    }
}

// ---------------------------------------------------------------------------
// pack Wih -> [gru][kt 16][gc 1536][32 k] f16, gc = jg*48 + gate*16 + jl
// ---------------------------------------------------------------------------
__global__ __launch_bounds__(256) void pack_wih_kernel(
    const float* __restrict__ Wih_s, const float* __restrict__ Wih_t,
    _Float16* __restrict__ wp) {
    int e = blockIdx.x * 256 + threadIdx.x;     // 2*16*1536*32
    int kk = e & 31;
    int t = e >> 5;
    int gc = t % 1536;
    int t2 = t / 1536;
    int kt = t2 & 15, gru = t2 >> 4;
    int jg = gc / 48, r48 = gc % 48;
    int gate = r48 >> 4, jl = r48 & 15;
    int j = jg * 16 + jl, k = kt * 32 + kk;
    const float* W = gru ? Wih_t : Wih_s;
    wp[e] = (_Float16)W[(size_t)(gate * 512 + j) * 512 + k];
}

// pack Whh -> [gru][ns 32][kt 16][gc 48][32 k] f16, gc = gate*16 + jl
__global__ __launch_bounds__(256) void pack_whh_kernel(
    const float* __restrict__ Whh_s, const float* __restrict__ Whh_t,
    _Float16* __restrict__ wp) {
    int e = blockIdx.x * 256 + threadIdx.x;     // 2*32*16*48*32
    int kk = e & 31;
    int t = e >> 5;
    int gc = t % 48;
    int t2 = t / 48;
    int kt = t2 & 15;
    int t3 = t2 >> 4;
    int ns = t3 & 31, gru = t3 >> 5;
    int gate = gc >> 4, jl = gc & 15;
    int j = ns * 16 + jl, k = kt * 32 + kk;
    const float* W = gru ? Whh_t : Whh_s;
    wp[e] = (_Float16)W[(size_t)(gate * 512 + j) * 512 + k];
}

// pe[gru][n][512] f16
__global__ __launch_bounds__(256) void pack_pe_kernel(
    const float* __restrict__ pos_s, const float* __restrict__ ch_s,
    const float* __restrict__ pos_t, const float* __restrict__ ch_t,
    _Float16* __restrict__ pe) {
    int e = blockIdx.x * 256 + threadIdx.x;     // 2*1024*512
    int k = e & 511;
    int n = (e >> 9) & 1023;
    int gru = e >> 19;
    int c = n & 31;
    const float* pos = gru ? pos_t : pos_s;
    const float* ch  = gru ? ch_t  : ch_s;
    float v = (k < 256) ? pos[k] : ch[c * 256 + (k - 256)];
    pe[e] = (_Float16)v;
}

// ---------------------------------------------------------------------------
// gi GEMM: gi[sl][gru][row][1536 gc] = A[row][512] * Wih_pack (no bias).
// mode 0: A = emb_buf[sl*2+gru]; mode 1: A = pe[gru], out gi_pe.
// 512 thr, tile 128M x 256gc, K=512 (16 kt x 32).
// ---------------------------------------------------------------------------
__global__ __launch_bounds__(512, 2) void gi_gemm_kernel(
    const _Float16* __restrict__ emb, const _Float16* __restrict__ pe,
    const _Float16* __restrict__ wih_pack,
    _Float16* __restrict__ gi, _Float16* __restrict__ gi_pe, int mode) {
    __shared__ __align__(16) char sA[8192];
    __shared__ __align__(16) char sB[16384];
    int Nt = blockIdx.x % 6, Mt = blockIdx.x / 6;
    int sl = blockIdx.y, gru = blockIdx.z;
    int tid = threadIdx.x, w = tid >> 6, lane = tid & 63;
    int wm = w & 3, wn = w >> 2, ml = lane & 15, qq = lane >> 4;

    const char* Ab = mode ? (const char*)(pe  + (size_t)gru * N_ * D_)
                          : (const char*)(emb + (size_t)(sl * 2 + gru) * N_ * D_);
    const char* Bb = (const char*)wih_pack + (size_t)(gru * 16) * 1536 * 64;
    _Float16* ob = mode ? gi_pe + (size_t)gru * N_ * 1536
                        : gi    + (size_t)(sl * 2 + gru) * N_ * 1536;

    // staging lanes (swizzled source, lane-contiguous dest)
    int cA = w * 64 + lane;
    int rA = cA >> 2, kqA = (cA & 3) ^ ((rA >> 1) & 3);
    const char* gA = Ab + (size_t)(Mt * 128 + rA) * 1024 + kqA * 16;
    int cB0 = w * 64 + lane, cB1 = 512 + cB0;
    int rB0 = cB0 >> 2, kqB0 = (cB0 & 3) ^ ((rB0 >> 1) & 3);
    int rB1 = cB1 >> 2, kqB1 = (cB1 & 3) ^ ((rB1 >> 1) & 3);

    int offA[2], offB[8];
#pragma unroll
    for (int mf = 0; mf < 2; ++mf) {
        int row = wm * 32 + mf * 16 + ml;
        offA[mf] = (row * 4 + (qq ^ ((row >> 1) & 3))) * 16;
    }
#pragma unroll
    for (int nf = 0; nf < 8; ++nf) {
        int gc = wn * 128 + nf * 16 + ml;
        offB[nf] = (gc * 4 + (qq ^ ((gc >> 1) & 3))) * 16;
    }

    f32x4 acc[2][8];
#pragma unroll
    for (int i = 0; i < 2; ++i)
#pragma unroll
        for (int nf = 0; nf < 8; ++nf) {
            f32x4 z = {0.f, 0.f, 0.f, 0.f};
            acc[i][nf] = z;
        }

    for (int kt = 0; kt < 16; ++kt) {
        __syncthreads();
        stage16(gA + kt * 64, sA + w * 1024);
        const char* Bkt = Bb + (size_t)kt * 98304 + (size_t)Nt * 16384;
        stage16(Bkt + rB0 * 64 + kqB0 * 16, sB + w * 1024);
        stage16(Bkt + rB1 * 64 + kqB1 * 16, sB + 8192 + w * 1024);
        asm volatile("s_waitcnt vmcnt(0)" ::: "memory");
        __syncthreads();
        f16x8 a0 = *(const f16x8*)(sA + offA[0]);
        f16x8 a1 = *(const f16x8*)(sA + offA[1]);
#pragma unroll
        for (int nf = 0; nf < 8; ++nf) {
            f16x8 b = *(const f16x8*)(sB + offB[nf]);
            acc[0][nf] = __builtin_amdgcn_mfma_f32_16x16x32_f16(a0, b, acc[0][nf], 0, 0, 0);
            acc[1][nf] = __builtin_amdgcn_mfma_f32_16x16x32_f16(a1, b, acc[1][nf], 0, 0, 0);
        }
    }

#pragma unroll
    for (int mf = 0; mf < 2; ++mf)
#pragma unroll
        for (int nf = 0; nf < 8; ++nf)
#pragma unroll
            for (int reg = 0; reg < 4; ++reg) {
                int row_g = Mt * 128 + wm * 32 + mf * 16 + qq * 4 + reg;
                int gcg = Nt * 256 + wn * 128 + nf * 16 + ml;
                ob[(size_t)row_g * 1536 + gcg] = (_Float16)acc[mf][nf][reg];
            }
}

// ---------------------------------------------------------------------------
// Persistent GRU scan: 512 blocks (gru 2 x ns 32 x ms 8), 256 thr.
// Whh slice (16 j x 3 gates x 512 k, f16, 48 KB) resident in LDS.
// Per step: gh = h @ Whh_slice^T via MFMA, fused gate epilogue with
// precomputed gi, hand-rolled device-scope grid barrier between steps.
// ---------------------------------------------------------------------------
__global__ __launch_bounds__(256, 2) void gru_scan_kernel(
    const _Float16* __restrict__ whh_pack, const _Float16* __restrict__ gi,
    const float* __restrict__ bih_s, const float* __restrict__ bhh_s,
    const float* __restrict__ bih_t, const float* __restrict__ bhh_t,
    _Float16* hbf0, _Float16* hbf1, float* hf0, float* hf1,
    unsigned* bar, int nsteps) {
    __shared__ __align__(16) char sW[49152];
    __shared__ __align__(16) char sA[8192];
    int bid = blockIdx.x;
    int ns = bid & 31, ms = (bid >> 5) & 7, gru = bid >> 8;
    int tid = threadIdx.x, w = tid >> 6, lane = tid & 63;
    int ml = lane & 15, qq = lane >> 4;

    // one-time Whh -> LDS (swizzled)
    const char* Wb = (const char*)whh_pack + (size_t)((gru * 32 + ns) * 16) * 48 * 64;
    for (int c = tid; c < 3072; c += 256) {
        int kt = c / 192, rem = c - kt * 192, gc = rem >> 2, slot = rem & 3;
        int kq = slot ^ ((gc >> 1) & 3);
        *(int4*)(sW + c * 16) = *(const int4*)(Wb + (size_t)(kt * 48 + gc) * 64 + kq * 16);
    }

    int c0 = w * 64 + lane, c1 = 256 + c0;
    int r0 = c0 >> 2, k0 = (c0 & 3) ^ ((r0 >> 1) & 3);
    int r1 = c1 >> 2, k1 = (c1 & 3) ^ ((r1 >> 1) & 3);

    int offA[2], offW[3];
#pragma unroll
    for (int mf = 0; mf < 2; ++mf) {
        int row = w * 32 + mf * 16 + ml;
        offA[mf] = (row * 4 + (qq ^ ((row >> 1) & 3))) * 16;
    }
#pragma unroll
    for (int g = 0; g < 3; ++g) {
        int gc = g * 16 + ml;
        offW[g] = (gc * 4 + (qq ^ ((gc >> 1) & 3))) * 16;
    }

    int j = ns * 16 + ml;
    const float* bi = gru ? bih_t : bih_s;
    const float* bh = gru ? bhh_t : bhh_s;
    float bir = bi[j], biz = bi[D_ + j], bin = bi[2 * D_ + j];
    float bhr = bh[j], bhz = bh[D_ + j], bhn = bh[2 * D_ + j];

    __syncthreads();

    for (int it = 0; it < nsteps; ++it) {
        const _Float16* hin = (it & 1) ? hbf1 : hbf0;
        const float* hfin   = (it & 1) ? hf1  : hf0;
        _Float16* hout      = (it & 1) ? hbf0 : hbf1;
        float* hfout        = (it & 1) ? hf0  : hf1;
        const char* hinB = (const char*)hin + ((size_t)gru * N_ + ms * 128) * 1024;

        f32x4 acc[2][3];
#pragma unroll
        for (int i = 0; i < 2; ++i)
#pragma unroll
            for (int g = 0; g < 3; ++g) {
                f32x4 z = {0.f, 0.f, 0.f, 0.f};
                acc[i][g] = z;
            }

        for (int kt = 0; kt < 16; ++kt) {
            __syncthreads();
            stage16(hinB + (size_t)r0 * 1024 + kt * 64 + k0 * 16, sA + w * 1024);
            stage16(hinB + (size_t)r1 * 1024 + kt * 64 + k1 * 16, sA + 4096 + w * 1024);
            asm volatile("s_waitcnt vmcnt(0)" ::: "memory");
            __syncthreads();
            f16x8 a0 = *(const f16x8*)(sA + offA[0]);
            f16x8 a1 = *(const f16x8*)(sA + offA[1]);
            const char* Wkt = sW + kt * 3072;
#pragma unroll
            for (int g = 0; g < 3; ++g) {
                f16x8 bw = *(const f16x8*)(Wkt + offW[g]);
                acc[0][g] = __builtin_amdgcn_mfma_f32_16x16x32_f16(a0, bw, acc[0][g], 0, 0, 0);
                acc[1][g] = __builtin_amdgcn_mfma_f32_16x16x32_f16(a1, bw, acc[1][g], 0, 0, 0);
            }
        }

        const _Float16* gib = gi + ((size_t)(it * 2 + gru) * N_ + ms * 128) * 1536;
#pragma unroll
        for (int mf = 0; mf < 2; ++mf)
#pragma unroll
            for (int reg = 0; reg < 4; ++reg) {
                int rl = w * 32 + mf * 16 + qq * 4 + reg;
                float gr = (float)gib[(size_t)rl * 1536 + ns * 48 + ml];
                float gz = (float)gib[(size_t)rl * 1536 + ns * 48 + 16 + ml];
                float gn = (float)gib[(size_t)rl * 1536 + ns * 48 + 32 + ml];
                size_t idx = ((size_t)gru * N_ + ms * 128 + rl) * D_ + j;
                float r = 1.f / (1.f + __expf(-(acc[mf][0][reg] + gr + bir + bhr)));
                float z = 1.f / (1.f + __expf(-(acc[mf][1][reg] + gz + biz + bhz)));
                float nn = tanhf(gn + bin + r * (acc[mf][2][reg] + bhn));
                float hp = hfin[idx];
                float hv = (1.f - z) * nn + z * hp;
                hfout[idx] = hv;
                hout[idx] = (_Float16)hv;
            }

        // grid barrier (sense-reversing, device scope)
        __threadfence();
        __syncthreads();
        if (tid == 0) {
            unsigned g = __hip_atomic_load(bar + 1, __ATOMIC_ACQUIRE, __HIP_MEMORY_SCOPE_AGENT);
            unsigned a = __hip_atomic_fetch_add(bar, 1u, __ATOMIC_ACQ_REL, __HIP_MEMORY_SCOPE_AGENT);
            if (a == 511u) {
                __hip_atomic_store(bar, 0u, __ATOMIC_RELAXED, __HIP_MEMORY_SCOPE_AGENT);
                __hip_atomic_store(bar + 1, g + 1u, __ATOMIC_RELEASE, __HIP_MEMORY_SCOPE_AGENT);
            } else {
                while (__hip_atomic_load(bar + 1, __ATOMIC_ACQUIRE, __HIP_MEMORY_SCOPE_AGENT) == g)
                    __builtin_amdgcn_s_sleep(4);
            }
        }
        __syncthreads();
        __threadfence();
    }
}

// ---------------------------------------------------------------------------
__global__ __launch_bounds__(256) void head_kernel(
    const float* __restrict__ hs2, const float* __restrict__ ht2,
    const float* __restrict__ Wps, const float* __restrict__ bps,
    const float* __restrict__ Wpt, const float* __restrict__ bpt,
    const float* __restrict__ x, float* __restrict__ out) {
    int g = blockIdx.x * 256 + threadIdx.x;
    int n = g >> 4, p = g & 15;
    int b = n >> 5, c = n & 31;
    const float* hs = hs2 + (size_t)n * D_;
    const float* ht = ht2 + (size_t)n * D_;
    const float* ws = Wps + (size_t)p * D_;
    const float* wt = Wpt + (size_t)p * D_;
    float acc = bps[p] + bpt[p];
    for (int k = 0; k < D_; ++k) acc += hs[k] * ws[k] + ht[k] * wt[k];
    float last = x[((size_t)b * L_ + (L_ - 1)) * C_ + c];
    out[((size_t)b * SEG_ + p) * C_ + c] = acc + last;
}

// ---------------------------------------------------------------------------
extern "C" void kernel_launch(void* const* d_in, const int* in_sizes, int n_in,
                              void* d_out, int out_size, void* d_ws, size_t ws_size,
                              hipStream_t stream) {
    const float* x     = (const float*)d_in[0];
    const float* W_emb = (const float*)d_in[1];
    const float* b_emb = (const float*)d_in[2];
    const float* Wih_s = (const float*)d_in[3];
    const float* Whh_s = (const float*)d_in[4];
    const float* bih_s = (const float*)d_in[5];
    const float* bhh_s = (const float*)d_in[6];
    const float* Wih_t = (const float*)d_in[7];
    const float* Whh_t = (const float*)d_in[8];
    const float* bih_t = (const float*)d_in[9];
    const float* bhh_t = (const float*)d_in[10];
    const float* pos_s = (const float*)d_in[11];
    const float* ch_s  = (const float*)d_in[12];
    const float* pos_t = (const float*)d_in[13];
    const float* ch_t  = (const float*)d_in[14];
    const float* Wps   = (const float*)d_in[15];
    const float* bps   = (const float*)d_in[16];
    const float* Wpt   = (const float*)d_in[17];
    const float* bpt   = (const float*)d_in[18];
    float* out = (float*)d_out;

    char* p = (char*)d_ws;
    float* xs_seg = (float*)p;          p += (size_t)SX_ * N_ * SEG_ * 4;       // 4 MB
    float* xt_seg = (float*)p;          p += (size_t)SX_ * N_ * SEG_ * 4;       // 4 MB
    _Float16* emb_buf = (_Float16*)p;   p += (size_t)16 * 2 * N_ * D_ * 2;      // 32 MB
    _Float16* gi_buf  = (_Float16*)p;   p += (size_t)16 * 2 * N_ * 1536 * 2;    // 96 MB
    _Float16* gi_pe   = (_Float16*)p;   p += (size_t)2 * N_ * 1536 * 2;         // 6 MB
    _Float16* pe_buf  = (_Float16*)p;   p += (size_t)2 * N_ * D_ * 2;           // 2 MB
    _Float16* wih_pk  = (_Float16*)p;   p += (size_t)2 * 16 * 1536 * 32 * 2;    // 3 MB
    _Float16* whh_pk  = (_Float16*)p;   p += (size_t)2 * 32 * 16 * 48 * 32 * 2; // 3 MB
    _Float16* hbf0 = (_Float16*)p;      p += (size_t)2 * N_ * D_ * 2;           // 2 MB
    _Float16* hbf1 = (_Float16*)p;      p += (size_t)2 * N_ * D_ * 2;           // 2 MB
    float* hf0 = (float*)p;             p += (size_t)2 * N_ * D_ * 4;           // 4 MB
    float* hf1 = (float*)p;             p += (size_t)2 * N_ * D_ * 4;           // 4 MB
    unsigned* bar = (unsigned*)p;       p += 256;

    hipMemsetAsync(hbf0, 0, (size_t)2 * N_ * D_ * 2, stream);
    hipMemsetAsync(hf0,  0, (size_t)2 * N_ * D_ * 4, stream);
    hipMemsetAsync(bar,  0, 256, stream);

    pack_wih_kernel<<<6144, 256, 0, stream>>>(Wih_s, Wih_t, wih_pk);
    pack_whh_kernel<<<6144, 256, 0, stream>>>(Whh_s, Whh_t, whh_pk);
    pack_pe_kernel<<<4096, 256, 0, stream>>>(pos_s, ch_s, pos_t, ch_t, pe_buf);
    prep_kernel<<<B_ * 4, 256, 0, stream>>>(x, xs_seg, xt_seg);

    for (int b = 0; b < 4; ++b) {
        emb_kernel<<<512, 256, 0, stream>>>(xs_seg, xt_seg, W_emb, b_emb, emb_buf, b * 16);
        gi_gemm_kernel<<<dim3(48, 16, 2), 512, 0, stream>>>(
            emb_buf, pe_buf, wih_pk, gi_buf, gi_pe, 0);
        gru_scan_kernel<<<512, 256, 0, stream>>>(
            whh_pk, gi_buf, bih_s, bhh_s, bih_t, bhh_t,
            hbf0, hbf1, hf0, hf1, bar, 16);
    }
    // decoder: gi from pe, one step (state in *0 -> out *1)
    gi_gemm_kernel<<<dim3(48, 1, 2), 512, 0, stream>>>(
        emb_buf, pe_buf, wih_pk, gi_buf, gi_pe, 1);
    gru_scan_kernel<<<512, 256, 0, stream>>>(
        whh_pk, gi_pe, bih_s, bhh_s, bih_t, bhh_t,
        hbf0, hbf1, hf0, hf1, bar, 1);

    head_kernel<<<N_ * SEG_ / 256, 256, 0, stream>>>(
        hf1, hf1 + (size_t)N_ * D_, Wps, bps, Wpt, bpt, x, out);
}

// Round 4
// 1735.941 us; speedup vs baseline: 5.2997x; 5.2997x over previous
//
#include <hip/hip_runtime.h>
#include <math.h>

#define B_   32
#define L_   1024
#define C_   32
#define D_   512
#define SEG_ 16
#define SX_  64
#define N_   1024   // B*C

typedef _Float16 f16x8 __attribute__((ext_vector_type(8)));
typedef float    f32x4 __attribute__((ext_vector_type(4)));

__device__ __forceinline__ void stage16(const void* g, void* l) {
    __builtin_amdgcn_global_load_lds((const __attribute__((address_space(1))) void*)g,
                                     (__attribute__((address_space(3))) void*)l, 16, 0, 0);
}

// ---------------------------------------------------------------------------
// prep: x (B,L,C) -> xs_seg, xt_seg fp32 (step, n, seg); channel-axis moving
// mean (reference semantics), window 25, edge replication.
// ---------------------------------------------------------------------------
__global__ __launch_bounds__(256) void prep_kernel(const float* __restrict__ x,
                                                   float* __restrict__ xs_seg,
                                                   float* __restrict__ xt_seg) {
    int b = blockIdx.x >> 2;
    int t = ((blockIdx.x & 3) << 8) + threadIdx.x;
    const float* xb    = x + (size_t)b * (L_ * C_);
    const float* xrow  = xb + (size_t)t * C_;
    const float* xlast = xb + (size_t)(L_ - 1) * C_;

    float diff[C_];
#pragma unroll
    for (int c = 0; c < C_; ++c) diff[c] = xrow[c] - xlast[c];
    float ps[C_ + 1];
    ps[0] = 0.f;
#pragma unroll
    for (int c = 0; c < C_; ++c) ps[c + 1] = ps[c] + diff[c];

    int s = t >> 4, q = t & 15;
#pragma unroll
    for (int c = 0; c < C_; ++c) {
        int lo = c - 12, hi = c + 12;
        float sum = ps[(hi < 31 ? hi : 31) + 1] - ps[lo > 0 ? lo : 0];
        if (lo < 0)  sum += (float)(-lo)     * diff[0];
        if (hi > 31) sum += (float)(hi - 31) * diff[31];
        float mean = sum * (1.0f / 25.0f);
        size_t idx = ((size_t)s * N_ + (size_t)(b * C_ + c)) * SEG_ + q;
        xt_seg[idx] = mean;
        xs_seg[idx] = diff[c] - mean;
    }
}

// ---------------------------------------------------------------------------
// emb batch: emb_buf[sl][gru][n][512] f16 = relu(xseg @ W_emb^T + b_emb)
// ---------------------------------------------------------------------------
__global__ __launch_bounds__(256) void emb_kernel(
    const float* __restrict__ xs_seg, const float* __restrict__ xt_seg,
    const float* __restrict__ W_emb, const float* __restrict__ b_emb,
    _Float16* __restrict__ emb_buf, int s0) {
    int bid = blockIdx.x;
    int gru = bid >> 8, sl = (bid >> 4) & 15, nch = bid & 15;
    int step = s0 + sl, n0 = nch * 64;
    const float* xseg = gru ? xt_seg : xs_seg;
    __shared__ float xl[64 * 16];
    int tid = threadIdx.x;
    const float* src = xseg + ((size_t)step * N_ + n0) * SEG_;
    for (int i = tid; i < 1024; i += 256) xl[i] = src[i];
    float w1[16], w2[16];
#pragma unroll
    for (int q = 0; q < 16; ++q) {
        w1[q] = W_emb[tid * 16 + q];
        w2[q] = W_emb[(tid + 256) * 16 + q];
    }
    float b1 = b_emb[tid], b2 = b_emb[tid + 256];
    __syncthreads();
    _Float16* dst = emb_buf + ((size_t)(sl * 2 + gru) * N_ + n0) * D_;
    for (int r = 0; r < 64; ++r) {
        float a1 = b1, a2 = b2;
#pragma unroll
        for (int q = 0; q < 16; ++q) {
            float xv = xl[r * 16 + q];
            a1 = fmaf(xv, w1[q], a1);
            a2 = fmaf(xv, w2[q], a2);
        }
        a1 = a1 > 0.f ? a1 : 0.f;
        a2 = a2 > 0.f ? a2 : 0.f;
        dst[(size_t)r * D_ + tid]       = (_Float16)a1;
        dst[(size_t)r * D_ + tid + 256] = (_Float16)a2;
    }
}

// ---------------------------------------------------------------------------
// pack Wih -> [gru][kt 16][gc 1536][32 k] f16, gc = jg*48 + gate*16 + jl
// ---------------------------------------------------------------------------
__global__ __launch_bounds__(256) void pack_wih_kernel(
    const float* __restrict__ Wih_s, const float* __restrict__ Wih_t,
    _Float16* __restrict__ wp) {
    int e = blockIdx.x * 256 + threadIdx.x;     // 2*16*1536*32
    int kk = e & 31;
    int t = e >> 5;
    int gc = t % 1536;
    int t2 = t / 1536;
    int kt = t2 & 15, gru = t2 >> 4;
    int jg = gc / 48, r48 = gc % 48;
    int gate = r48 >> 4, jl = r48 & 15;
    int j = jg * 16 + jl, k = kt * 32 + kk;
    const float* W = gru ? Wih_t : Wih_s;
    wp[e] = (_Float16)W[(size_t)(gate * 512 + j) * 512 + k];
}

// pack Whh for step kernel: [gru][Nt 16][kt 16][gc 96][k 32] f16
// gc = jgl*48 + gate*16 + jl, j = (Nt*2+jgl)*16 + jl
__global__ __launch_bounds__(256) void pack_whh2_kernel(
    const float* __restrict__ Whh_s, const float* __restrict__ Whh_t,
    _Float16* __restrict__ wp) {
    int e = blockIdx.x * 256 + threadIdx.x;     // 2*16*16*96*32 = 1572864
    int kk = e & 31;
    int t = e >> 5;
    int gc = t % 96;
    int t2 = t / 96;
    int kt = t2 & 15;
    int t3 = t2 >> 4;
    int Nt = t3 & 15, gru = t3 >> 4;
    int jgl = gc / 48, r48 = gc % 48;
    int gate = r48 >> 4, jl = r48 & 15;
    int j = (Nt * 2 + jgl) * 16 + jl, k = kt * 32 + kk;
    const float* W = gru ? Whh_t : Whh_s;
    wp[e] = (_Float16)W[(size_t)(gate * 512 + j) * 512 + k];
}

// pe[gru][n][512] f16
__global__ __launch_bounds__(256) void pack_pe_kernel(
    const float* __restrict__ pos_s, const float* __restrict__ ch_s,
    const float* __restrict__ pos_t, const float* __restrict__ ch_t,
    _Float16* __restrict__ pe) {
    int e = blockIdx.x * 256 + threadIdx.x;     // 2*1024*512
    int k = e & 511;
    int n = (e >> 9) & 1023;
    int gru = e >> 19;
    int c = n & 31;
    const float* pos = gru ? pos_t : pos_s;
    const float* ch  = gru ? ch_t  : ch_s;
    float v = (k < 256) ? pos[k] : ch[c * 256 + (k - 256)];
    pe[e] = (_Float16)v;
}

// ---------------------------------------------------------------------------
// gi GEMM: gi[sl][gru][row][1536 gc] = A[row][512] * Wih_pack (no bias).
// mode 0: A = emb_buf[sl*2+gru]; mode 1: A = pe[gru], out gi_pe.
// 512 thr, tile 128M x 256gc, K=512 (16 kt x 32).
// ---------------------------------------------------------------------------
__global__ __launch_bounds__(512, 2) void gi_gemm_kernel(
    const _Float16* __restrict__ emb, const _Float16* __restrict__ pe,
    const _Float16* __restrict__ wih_pack,
    _Float16* __restrict__ gi, _Float16* __restrict__ gi_pe, int mode) {
    __shared__ __align__(16) char sA[8192];
    __shared__ __align__(16) char sB[16384];
    int Nt = blockIdx.x % 6, Mt = blockIdx.x / 6;
    int sl = blockIdx.y, gru = blockIdx.z;
    int tid = threadIdx.x, w = tid >> 6, lane = tid & 63;
    int wm = w & 3, wn = w >> 2, ml = lane & 15, qq = lane >> 4;

    const char* Ab = mode ? (const char*)(pe  + (size_t)gru * N_ * D_)
                          : (const char*)(emb + (size_t)(sl * 2 + gru) * N_ * D_);
    const char* Bb = (const char*)wih_pack + (size_t)(gru * 16) * 1536 * 64;
    _Float16* ob = mode ? gi_pe + (size_t)gru * N_ * 1536
                        : gi    + (size_t)(sl * 2 + gru) * N_ * 1536;

    int cA = w * 64 + lane;
    int rA = cA >> 2, kqA = (cA & 3) ^ ((rA >> 1) & 3);
    const char* gA = Ab + (size_t)(Mt * 128 + rA) * 1024 + kqA * 16;
    int cB0 = w * 64 + lane, cB1 = 512 + cB0;
    int rB0 = cB0 >> 2, kqB0 = (cB0 & 3) ^ ((rB0 >> 1) & 3);
    int rB1 = cB1 >> 2, kqB1 = (cB1 & 3) ^ ((rB1 >> 1) & 3);

    int offA[2], offB[8];
#pragma unroll
    for (int mf = 0; mf < 2; ++mf) {
        int row = wm * 32 + mf * 16 + ml;
        offA[mf] = (row * 4 + (qq ^ ((row >> 1) & 3))) * 16;
    }
#pragma unroll
    for (int nf = 0; nf < 8; ++nf) {
        int gc = wn * 128 + nf * 16 + ml;
        offB[nf] = (gc * 4 + (qq ^ ((gc >> 1) & 3))) * 16;
    }

    f32x4 acc[2][8];
#pragma unroll
    for (int i = 0; i < 2; ++i)
#pragma unroll
        for (int nf = 0; nf < 8; ++nf) {
            f32x4 z = {0.f, 0.f, 0.f, 0.f};
            acc[i][nf] = z;
        }

    for (int kt = 0; kt < 16; ++kt) {
        __syncthreads();
        stage16(gA + kt * 64, sA + w * 1024);
        const char* Bkt = Bb + (size_t)kt * 98304 + (size_t)Nt * 16384;
        stage16(Bkt + rB0 * 64 + kqB0 * 16, sB + w * 1024);
        stage16(Bkt + rB1 * 64 + kqB1 * 16, sB + 8192 + w * 1024);
        asm volatile("s_waitcnt vmcnt(0)" ::: "memory");
        __syncthreads();
        f16x8 a0 = *(const f16x8*)(sA + offA[0]);
        f16x8 a1 = *(const f16x8*)(sA + offA[1]);
#pragma unroll
        for (int nf = 0; nf < 8; ++nf) {
            f16x8 b = *(const f16x8*)(sB + offB[nf]);
            acc[0][nf] = __builtin_amdgcn_mfma_f32_16x16x32_f16(a0, b, acc[0][nf], 0, 0, 0);
            acc[1][nf] = __builtin_amdgcn_mfma_f32_16x16x32_f16(a1, b, acc[1][nf], 0, 0, 0);
        }
    }

#pragma unroll
    for (int mf = 0; mf < 2; ++mf)
#pragma unroll
        for (int nf = 0; nf < 8; ++nf)
#pragma unroll
            for (int reg = 0; reg < 4; ++reg) {
                int row_g = Mt * 128 + wm * 32 + mf * 16 + qq * 4 + reg;
                int gcg = Nt * 256 + wn * 128 + nf * 16 + ml;
                ob[(size_t)row_g * 1536 + gcg] = (_Float16)acc[mf][nf][reg];
            }
}

// ---------------------------------------------------------------------------
// One recurrent GRU step (both GRUs via blockIdx.z). Launch = the sync.
// gh = h @ WhhP (K=512, N=1536 packed gates), fused epilogue w/ hoisted gi.
// grid (16 Nt, 8 Mt, 2 gru) = 256 blocks (1/CU); tile 128M x 96gc;
// wave w: rows w*32..+32, all 96 gc -> acc[2][6] (g = jgl*3 + gate).
// ---------------------------------------------------------------------------
__global__ __launch_bounds__(256) void gru_step_mfma(
    const _Float16* __restrict__ whh_pk2,   // [gru][Nt16][kt16][96][32]
    const _Float16* __restrict__ gi_step,   // [gru][1024][1536]
    const float* __restrict__ bih_s, const float* __restrict__ bhh_s,
    const float* __restrict__ bih_t, const float* __restrict__ bhh_t,
    const _Float16* __restrict__ hbf_in, const float* __restrict__ hf_in,
    _Float16* __restrict__ hbf_out, float* __restrict__ hf_out) {
    __shared__ __align__(16) char sA[8192];
    __shared__ __align__(16) char sB[6144];
    int Nt = blockIdx.x, Mt = blockIdx.y, gru = blockIdx.z;
    int tid = threadIdx.x, w = tid >> 6, lane = tid & 63;
    int ml = lane & 15, qq = lane >> 4;

    const char* hinB = (const char*)hbf_in + ((size_t)gru * N_ + Mt * 128) * 1024;
    const char* Bb   = (const char*)whh_pk2 + (size_t)(gru * 16 + Nt) * 16 * 6144;

    // A staging: 512 chunks (2 rounds of 256)
    int cA0 = w * 64 + lane;
    int rA0 = cA0 >> 2, kA0 = (cA0 & 3) ^ ((rA0 >> 1) & 3);
    int cA1 = 256 + cA0;
    int rA1 = cA1 >> 2, kA1 = (cA1 & 3) ^ ((rA1 >> 1) & 3);
    // B staging: 384 chunks (round 0 all waves, round 1 waves 0-1)
    int cB0 = w * 64 + lane;
    int gB0 = cB0 >> 2, kB0 = (cB0 & 3) ^ ((gB0 >> 1) & 3);
    int cB1 = 256 + cB0;
    int gB1 = cB1 >> 2, kB1 = (cB1 & 3) ^ ((gB1 >> 1) & 3);

    int offA[2], offB[6];
#pragma unroll
    for (int mf = 0; mf < 2; ++mf) {
        int row = w * 32 + mf * 16 + ml;
        offA[mf] = (row * 4 + (qq ^ ((row >> 1) & 3))) * 16;
    }
#pragma unroll
    for (int g = 0; g < 6; ++g) {
        int gc = g * 16 + ml;
        offB[g] = (gc * 4 + (qq ^ ((gc >> 1) & 3))) * 16;
    }

    f32x4 acc[2][6];
#pragma unroll
    for (int i = 0; i < 2; ++i)
#pragma unroll
        for (int g = 0; g < 6; ++g) {
            f32x4 z = {0.f, 0.f, 0.f, 0.f};
            acc[i][g] = z;
        }

    for (int kt = 0; kt < 16; ++kt) {
        __syncthreads();
        stage16(hinB + (size_t)rA0 * 1024 + kt * 64 + kA0 * 16, sA + w * 1024);
        stage16(hinB + (size_t)rA1 * 1024 + kt * 64 + kA1 * 16, sA + 4096 + w * 1024);
        const char* Bkt = Bb + kt * 6144;
        stage16(Bkt + gB0 * 64 + kB0 * 16, sB + w * 1024);
        if (w < 2) stage16(Bkt + gB1 * 64 + kB1 * 16, sB + 4096 + w * 1024);
        asm volatile("s_waitcnt vmcnt(0)" ::: "memory");
        __syncthreads();
        f16x8 a0 = *(const f16x8*)(sA + offA[0]);
        f16x8 a1 = *(const f16x8*)(sA + offA[1]);
#pragma unroll
        for (int g = 0; g < 6; ++g) {
            f16x8 b = *(const f16x8*)(sB + offB[g]);
            acc[0][g] = __builtin_amdgcn_mfma_f32_16x16x32_f16(a0, b, acc[0][g], 0, 0, 0);
            acc[1][g] = __builtin_amdgcn_mfma_f32_16x16x32_f16(a1, b, acc[1][g], 0, 0, 0);
        }
    }

    const float* bi = gru ? bih_t : bih_s;
    const float* bh = gru ? bhh_t : bhh_s;
    const _Float16* gib = gi_step + (size_t)gru * N_ * 1536;
#pragma unroll
    for (int jgl = 0; jgl < 2; ++jgl) {
        int j = (Nt * 2 + jgl) * 16 + ml;
        float bir = bi[j], biz = bi[D_ + j], bin = bi[2 * D_ + j];
        float bhr = bh[j], bhz = bh[D_ + j], bhn = bh[2 * D_ + j];
#pragma unroll
        for (int mf = 0; mf < 2; ++mf)
#pragma unroll
            for (int reg = 0; reg < 4; ++reg) {
                int row = Mt * 128 + w * 32 + mf * 16 + qq * 4 + reg;
                size_t gb = (size_t)row * 1536 + Nt * 96 + jgl * 48 + ml;
                float gr = (float)gib[gb];
                float gz = (float)gib[gb + 16];
                float gn = (float)gib[gb + 32];
                size_t idx = ((size_t)gru * N_ + row) * D_ + j;
                float r = 1.f / (1.f + __expf(-(acc[mf][jgl * 3 + 0][reg] + gr + bir + bhr)));
                float z = 1.f / (1.f + __expf(-(acc[mf][jgl * 3 + 1][reg] + gz + biz + bhz)));
                float nn = tanhf(gn + bin + r * (acc[mf][jgl * 3 + 2][reg] + bhn));
                float hp = hf_in[idx];
                float hv = (1.f - z) * nn + z * hp;
                hf_out[idx] = hv;
                hbf_out[idx] = (_Float16)hv;
            }
    }
}

// ---------------------------------------------------------------------------
__global__ __launch_bounds__(256) void head_kernel(
    const float* __restrict__ hs2, const float* __restrict__ ht2,
    const float* __restrict__ Wps, const float* __restrict__ bps,
    const float* __restrict__ Wpt, const float* __restrict__ bpt,
    const float* __restrict__ x, float* __restrict__ out) {
    int g = blockIdx.x * 256 + threadIdx.x;
    int n = g >> 4, p = g & 15;
    int b = n >> 5, c = n & 31;
    const float* hs = hs2 + (size_t)n * D_;
    const float* ht = ht2 + (size_t)n * D_;
    const float* ws = Wps + (size_t)p * D_;
    const float* wt = Wpt + (size_t)p * D_;
    float acc = bps[p] + bpt[p];
    for (int k = 0; k < D_; ++k) acc += hs[k] * ws[k] + ht[k] * wt[k];
    float last = x[((size_t)b * L_ + (L_ - 1)) * C_ + c];
    out[((size_t)b * SEG_ + p) * C_ + c] = acc + last;
}

// ---------------------------------------------------------------------------
extern "C" void kernel_launch(void* const* d_in, const int* in_sizes, int n_in,
                              void* d_out, int out_size, void* d_ws, size_t ws_size,
                              hipStream_t stream) {
    const float* x     = (const float*)d_in[0];
    const float* W_emb = (const float*)d_in[1];
    const float* b_emb = (const float*)d_in[2];
    const float* Wih_s = (const float*)d_in[3];
    const float* Whh_s = (const float*)d_in[4];
    const float* bih_s = (const float*)d_in[5];
    const float* bhh_s = (const float*)d_in[6];
    const float* Wih_t = (const float*)d_in[7];
    const float* Whh_t = (const float*)d_in[8];
    const float* bih_t = (const float*)d_in[9];
    const float* bhh_t = (const float*)d_in[10];
    const float* pos_s = (const float*)d_in[11];
    const float* ch_s  = (const float*)d_in[12];
    const float* pos_t = (const float*)d_in[13];
    const float* ch_t  = (const float*)d_in[14];
    const float* Wps   = (const float*)d_in[15];
    const float* bps   = (const float*)d_in[16];
    const float* Wpt   = (const float*)d_in[17];
    const float* bpt   = (const float*)d_in[18];
    float* out = (float*)d_out;

    char* p = (char*)d_ws;
    float* xs_seg = (float*)p;          p += (size_t)SX_ * N_ * SEG_ * 4;       // 4 MB
    float* xt_seg = (float*)p;          p += (size_t)SX_ * N_ * SEG_ * 4;       // 4 MB
    _Float16* emb_buf = (_Float16*)p;   p += (size_t)16 * 2 * N_ * D_ * 2;      // 32 MB
    _Float16* gi_buf  = (_Float16*)p;   p += (size_t)16 * 2 * N_ * 1536 * 2;    // 96 MB
    _Float16* gi_pe   = (_Float16*)p;   p += (size_t)2 * N_ * 1536 * 2;         // 6 MB
    _Float16* pe_buf  = (_Float16*)p;   p += (size_t)2 * N_ * D_ * 2;           // 2 MB
    _Float16* wih_pk  = (_Float16*)p;   p += (size_t)2 * 16 * 1536 * 32 * 2;    // 3 MB
    _Float16* whh_pk2 = (_Float16*)p;   p += (size_t)2 * 16 * 16 * 96 * 32 * 2; // 3 MB
    _Float16* hbf0 = (_Float16*)p;      p += (size_t)2 * N_ * D_ * 2;           // 2 MB
    _Float16* hbf1 = (_Float16*)p;      p += (size_t)2 * N_ * D_ * 2;           // 2 MB
    float* hf0 = (float*)p;             p += (size_t)2 * N_ * D_ * 4;           // 4 MB
    float* hf1 = (float*)p;             p += (size_t)2 * N_ * D_ * 4;           // 4 MB

    hipMemsetAsync(hbf0, 0, (size_t)2 * N_ * D_ * 2, stream);
    hipMemsetAsync(hf0,  0, (size_t)2 * N_ * D_ * 4, stream);

    pack_wih_kernel<<<6144, 256, 0, stream>>>(Wih_s, Wih_t, wih_pk);
    pack_whh2_kernel<<<6144, 256, 0, stream>>>(Whh_s, Whh_t, whh_pk2);
    pack_pe_kernel<<<4096, 256, 0, stream>>>(pos_s, ch_s, pos_t, ch_t, pe_buf);
    prep_kernel<<<B_ * 4, 256, 0, stream>>>(x, xs_seg, xt_seg);

    dim3 sgrid(16, 8, 2);
    for (int b = 0; b < 4; ++b) {
        emb_kernel<<<512, 256, 0, stream>>>(xs_seg, xt_seg, W_emb, b_emb, emb_buf, b * 16);
        gi_gemm_kernel<<<dim3(48, 16, 2), 512, 0, stream>>>(
            emb_buf, pe_buf, wih_pk, gi_buf, gi_pe, 0);
        for (int sl = 0; sl < 16; ++sl) {
            int it = b * 16 + sl;
            const _Float16* hbin = (it & 1) ? hbf1 : hbf0;
            _Float16* hbout      = (it & 1) ? hbf0 : hbf1;
            const float* hfin    = (it & 1) ? hf1 : hf0;
            float* hfout         = (it & 1) ? hf0 : hf1;
            gru_step_mfma<<<sgrid, 256, 0, stream>>>(
                whh_pk2, gi_buf + (size_t)sl * 2 * N_ * 1536,
                bih_s, bhh_s, bih_t, bhh_t, hbin, hfin, hbout, hfout);
        }
    }
    // decoder: gi from pe; state in *0 -> write *1
    gi_gemm_kernel<<<dim3(48, 1, 2), 512, 0, stream>>>(
        emb_buf, pe_buf, wih_pk, gi_buf, gi_pe, 1);
    gru_step_mfma<<<sgrid, 256, 0, stream>>>(
        whh_pk2, gi_pe, bih_s, bhh_s, bih_t, bhh_t, hbf0, hf0, hbf1, hf1);

    head_kernel<<<N_ * SEG_ / 256, 256, 0, stream>>>(
        hf1, hf1 + (size_t)N_ * D_, Wps, bps, Wpt, bpt, x, out);
}

// Round 5
// 1209.392 us; speedup vs baseline: 7.6070x; 1.4354x over previous
//
#include <hip/hip_runtime.h>
#include <math.h>

#define B_   32
#define L_   1024
#define C_   32
#define D_   512
#define SEG_ 16
#define SX_  64
#define N_   1024   // B*C

typedef _Float16 f16x8 __attribute__((ext_vector_type(8)));
typedef float    f32x4 __attribute__((ext_vector_type(4)));

__device__ __forceinline__ void stage16(const void* g, void* l) {
    __builtin_amdgcn_global_load_lds((const __attribute__((address_space(1))) void*)g,
                                     (__attribute__((address_space(3))) void*)l, 16, 0, 0);
}

// ---------------------------------------------------------------------------
// prep: x (B,L,C) -> xs_seg, xt_seg fp32 (step, n, seg); channel-axis moving
// mean (reference semantics), window 25, edge replication.
// ---------------------------------------------------------------------------
__global__ __launch_bounds__(256) void prep_kernel(const float* __restrict__ x,
                                                   float* __restrict__ xs_seg,
                                                   float* __restrict__ xt_seg) {
    int b = blockIdx.x >> 2;
    int t = ((blockIdx.x & 3) << 8) + threadIdx.x;
    const float* xb    = x + (size_t)b * (L_ * C_);
    const float* xrow  = xb + (size_t)t * C_;
    const float* xlast = xb + (size_t)(L_ - 1) * C_;

    float diff[C_];
#pragma unroll
    for (int c = 0; c < C_; ++c) diff[c] = xrow[c] - xlast[c];
    float ps[C_ + 1];
    ps[0] = 0.f;
#pragma unroll
    for (int c = 0; c < C_; ++c) ps[c + 1] = ps[c] + diff[c];

    int s = t >> 4, q = t & 15;
#pragma unroll
    for (int c = 0; c < C_; ++c) {
        int lo = c - 12, hi = c + 12;
        float sum = ps[(hi < 31 ? hi : 31) + 1] - ps[lo > 0 ? lo : 0];
        if (lo < 0)  sum += (float)(-lo)     * diff[0];
        if (hi > 31) sum += (float)(hi - 31) * diff[31];
        float mean = sum * (1.0f / 25.0f);
        size_t idx = ((size_t)s * N_ + (size_t)(b * C_ + c)) * SEG_ + q;
        xt_seg[idx] = mean;
        xs_seg[idx] = diff[c] - mean;
    }
}

// ---------------------------------------------------------------------------
// emb batch: emb_buf[sl][gru][n][512] f16 = relu(xseg @ W_emb^T + b_emb)
// ---------------------------------------------------------------------------
__global__ __launch_bounds__(256) void emb_kernel(
    const float* __restrict__ xs_seg, const float* __restrict__ xt_seg,
    const float* __restrict__ W_emb, const float* __restrict__ b_emb,
    _Float16* __restrict__ emb_buf, int s0) {
    int bid = blockIdx.x;
    int gru = bid >> 8, sl = (bid >> 4) & 15, nch = bid & 15;
    int step = s0 + sl, n0 = nch * 64;
    const float* xseg = gru ? xt_seg : xs_seg;
    __shared__ float xl[64 * 16];
    int tid = threadIdx.x;
    const float* src = xseg + ((size_t)step * N_ + n0) * SEG_;
    for (int i = tid; i < 1024; i += 256) xl[i] = src[i];
    float w1[16], w2[16];
#pragma unroll
    for (int q = 0; q < 16; ++q) {
        w1[q] = W_emb[tid * 16 + q];
        w2[q] = W_emb[(tid + 256) * 16 + q];
    }
    float b1 = b_emb[tid], b2 = b_emb[tid + 256];
    __syncthreads();
    _Float16* dst = emb_buf + ((size_t)(sl * 2 + gru) * N_ + n0) * D_;
    for (int r = 0; r < 64; ++r) {
        float a1 = b1, a2 = b2;
#pragma unroll
        for (int q = 0; q < 16; ++q) {
            float xv = xl[r * 16 + q];
            a1 = fmaf(xv, w1[q], a1);
            a2 = fmaf(xv, w2[q], a2);
        }
        a1 = a1 > 0.f ? a1 : 0.f;
        a2 = a2 > 0.f ? a2 : 0.f;
        dst[(size_t)r * D_ + tid]       = (_Float16)a1;
        dst[(size_t)r * D_ + tid + 256] = (_Float16)a2;
    }
}

// ---------------------------------------------------------------------------
// pack Wih -> [gru][kt 16][gc 1536][32 k] f16, gc = jg*48 + gate*16 + jl
// ---------------------------------------------------------------------------
__global__ __launch_bounds__(256) void pack_wih_kernel(
    const float* __restrict__ Wih_s, const float* __restrict__ Wih_t,
    _Float16* __restrict__ wp) {
    int e = blockIdx.x * 256 + threadIdx.x;     // 2*16*1536*32
    int kk = e & 31;
    int t = e >> 5;
    int gc = t % 1536;
    int t2 = t / 1536;
    int kt = t2 & 15, gru = t2 >> 4;
    int jg = gc / 48, r48 = gc % 48;
    int gate = r48 >> 4, jl = r48 & 15;
    int j = jg * 16 + jl, k = kt * 32 + kk;
    const float* W = gru ? Wih_t : Wih_s;
    wp[e] = (_Float16)W[(size_t)(gate * 512 + j) * 512 + k];
}

// ---------------------------------------------------------------------------
// pack Whh pre-swizzled for step kernel: [gru][Nt 16][kt 8][chunk 768][8 f16]
// chunk c: gc = c>>3, qs = c&7, global quad q = qs ^ (gc&7);
// gc = jgl*48 + gate*16 + jl, j = (Nt*2+jgl)*16+jl, k = kt*64 + q*8 + fi.
// Staging then copies linearly; LDS ends up XOR-swizzled for free.
// ---------------------------------------------------------------------------
__global__ __launch_bounds__(256) void pack_whh3_kernel(
    const float* __restrict__ Whh_s, const float* __restrict__ Whh_t,
    _Float16* __restrict__ wp) {
    int e = blockIdx.x * 256 + threadIdx.x;     // 2*16*8*768*8 = 1572864
    int fi = e & 7;
    int t = e >> 3;
    int c = t % 768;
    int t2 = t / 768;
    int kt = t2 & 7;
    int Nt = (t2 >> 3) & 15;
    int gru = t2 >> 7;
    int gc = c >> 3, qs = c & 7;
    int q = qs ^ (gc & 7);
    int k = kt * 64 + q * 8 + fi;
    int jgl = gc / 48, r48 = gc % 48;
    int gate = r48 >> 4, jl = r48 & 15;
    int j = (Nt * 2 + jgl) * 16 + jl;
    const float* W = gru ? Whh_t : Whh_s;
    wp[e] = (_Float16)W[(size_t)(gate * 512 + j) * 512 + k];
}

// pe[gru][n][512] f16
__global__ __launch_bounds__(256) void pack_pe_kernel(
    const float* __restrict__ pos_s, const float* __restrict__ ch_s,
    const float* __restrict__ pos_t, const float* __restrict__ ch_t,
    _Float16* __restrict__ pe) {
    int e = blockIdx.x * 256 + threadIdx.x;     // 2*1024*512
    int k = e & 511;
    int n = (e >> 9) & 1023;
    int gru = e >> 19;
    int c = n & 31;
    const float* pos = gru ? pos_t : pos_s;
    const float* ch  = gru ? ch_t  : ch_s;
    float v = (k < 256) ? pos[k] : ch[c * 256 + (k - 256)];
    pe[e] = (_Float16)v;
}

// ---------------------------------------------------------------------------
// gi GEMM: gi[sl][gru][row][1536 gc] = A[row][512] * Wih_pack (no bias).
// mode 0: A = emb_buf[sl*2+gru]; mode 1: A = pe[gru], out gi_pe.
// 512 thr, tile 128M x 256gc, K=512. Block map: Mt = x%8 -> XCD = Mt, so
// each XCD keeps the full 3 MB B resident in its L2 across all sl.
// ---------------------------------------------------------------------------
__global__ __launch_bounds__(512, 2) void gi_gemm_kernel(
    const _Float16* __restrict__ emb, const _Float16* __restrict__ pe,
    const _Float16* __restrict__ wih_pack,
    _Float16* __restrict__ gi, _Float16* __restrict__ gi_pe, int mode) {
    __shared__ __align__(16) char sA[8192];
    __shared__ __align__(16) char sB[16384];
    int Mt = blockIdx.x & 7, Nt = blockIdx.x >> 3;
    int sl = blockIdx.y, gru = blockIdx.z;
    int tid = threadIdx.x, w = tid >> 6, lane = tid & 63;
    int wm = w & 3, wn = w >> 2, ml = lane & 15, qq = lane >> 4;

    const char* Ab = mode ? (const char*)(pe  + (size_t)gru * N_ * D_)
                          : (const char*)(emb + (size_t)(sl * 2 + gru) * N_ * D_);
    const char* Bb = (const char*)wih_pack + (size_t)(gru * 16) * 1536 * 64;
    _Float16* ob = mode ? gi_pe + (size_t)gru * N_ * 1536
                        : gi    + (size_t)(sl * 2 + gru) * N_ * 1536;

    int cA = w * 64 + lane;
    int rA = cA >> 2, kqA = (cA & 3) ^ ((rA >> 1) & 3);
    const char* gA = Ab + (size_t)(Mt * 128 + rA) * 1024 + kqA * 16;
    int cB0 = w * 64 + lane, cB1 = 512 + cB0;
    int rB0 = cB0 >> 2, kqB0 = (cB0 & 3) ^ ((rB0 >> 1) & 3);
    int rB1 = cB1 >> 2, kqB1 = (cB1 & 3) ^ ((rB1 >> 1) & 3);

    int offA[2], offB[8];
#pragma unroll
    for (int mf = 0; mf < 2; ++mf) {
        int row = wm * 32 + mf * 16 + ml;
        offA[mf] = (row * 4 + (qq ^ ((row >> 1) & 3))) * 16;
    }
#pragma unroll
    for (int nf = 0; nf < 8; ++nf) {
        int gc = wn * 128 + nf * 16 + ml;
        offB[nf] = (gc * 4 + (qq ^ ((gc >> 1) & 3))) * 16;
    }

    f32x4 acc[2][8];
#pragma unroll
    for (int i = 0; i < 2; ++i)
#pragma unroll
        for (int nf = 0; nf < 8; ++nf) {
            f32x4 z = {0.f, 0.f, 0.f, 0.f};
            acc[i][nf] = z;
        }

    for (int kt = 0; kt < 16; ++kt) {
        __syncthreads();
        stage16(gA + kt * 64, sA + w * 1024);
        const char* Bkt = Bb + (size_t)kt * 98304 + (size_t)Nt * 16384;
        stage16(Bkt + rB0 * 64 + kqB0 * 16, sB + w * 1024);
        stage16(Bkt + rB1 * 64 + kqB1 * 16, sB + 8192 + w * 1024);
        asm volatile("s_waitcnt vmcnt(0)" ::: "memory");
        __syncthreads();
        f16x8 a0 = *(const f16x8*)(sA + offA[0]);
        f16x8 a1 = *(const f16x8*)(sA + offA[1]);
#pragma unroll
        for (int nf = 0; nf < 8; ++nf) {
            f16x8 b = *(const f16x8*)(sB + offB[nf]);
            acc[0][nf] = __builtin_amdgcn_mfma_f32_16x16x32_f16(a0, b, acc[0][nf], 0, 0, 0);
            acc[1][nf] = __builtin_amdgcn_mfma_f32_16x16x32_f16(a1, b, acc[1][nf], 0, 0, 0);
        }
    }

#pragma unroll
    for (int mf = 0; mf < 2; ++mf)
#pragma unroll
        for (int nf = 0; nf < 8; ++nf)
#pragma unroll
            for (int reg = 0; reg < 4; ++reg) {
                int row_g = Mt * 128 + wm * 32 + mf * 16 + qq * 4 + reg;
                int gcg = Nt * 256 + wn * 128 + nf * 16 + ml;
                ob[(size_t)row_g * 1536 + gcg] = (_Float16)acc[mf][nf][reg];
            }
}

// ---------------------------------------------------------------------------
// One recurrent GRU step. grid (16 Nt, 16 Mt, 2 gru) = 512 blocks (2/CU).
// Tile 64M x 96gc, BK=64 (8 k-iters). h is f16-only. Whh pre-swizzled in
// global, so B staging is a linear global_load_lds burst. XCD = id%8 = Nt%8
// pins B slices (384 KB/XCD) in L2 across the whole scan.
// ---------------------------------------------------------------------------
__global__ __launch_bounds__(256) void gru_step_mfma(
    const _Float16* __restrict__ whh_pk3,   // [gru][Nt16][kt8][768 chunks][8]
    const _Float16* __restrict__ gi_step,   // [gru][1024][1536]
    const float* __restrict__ bih_s, const float* __restrict__ bhh_s,
    const float* __restrict__ bih_t, const float* __restrict__ bhh_t,
    const _Float16* __restrict__ hbf_in, _Float16* __restrict__ hbf_out) {
    __shared__ __align__(16) char sA[8192];
    __shared__ __align__(16) char sB[12288];
    int Nt = blockIdx.x, Mt = blockIdx.y, gru = blockIdx.z;
    int tid = threadIdx.x, w = tid >> 6, lane = tid & 63;
    int ml = lane & 15, qq = lane >> 4;

    const char* hinB = (const char*)hbf_in + ((size_t)gru * N_ + Mt * 64) * 1024;
    const char* BbL  = (const char*)whh_pk3 + (size_t)(gru * 16 + Nt) * 8 * 12288
                       + lane * 16;

    // A staging (2 rounds of 256 chunks): LDS chunk c -> global quad c&7 ^ row&7
    int c0 = w * 64 + lane, c1 = c0 + 256;
    int rA0 = c0 >> 3, qA0 = (c0 & 7) ^ (rA0 & 7);
    int rA1 = c1 >> 3, qA1 = (c1 & 7) ^ (rA1 & 7);
    const char* gA0 = hinB + rA0 * 1024 + qA0 * 16;
    const char* gA1 = hinB + rA1 * 1024 + qA1 * 16;

    // fragment offsets (XOR-8 swizzle)
    int rowA = w * 16 + ml;
    int offA0 = rowA * 128 + ((qq)     ^ (ml & 7)) * 16;
    int offA1 = rowA * 128 + ((4 + qq) ^ (ml & 7)) * 16;
    int offB[6][2];
#pragma unroll
    for (int g = 0; g < 6; ++g) {
        int gc = g * 16 + ml;
#pragma unroll
        for (int f = 0; f < 2; ++f)
            offB[g][f] = gc * 128 + ((f * 4 + qq) ^ (gc & 7)) * 16;
    }

    f32x4 acc[6];
#pragma unroll
    for (int g = 0; g < 6; ++g) {
        f32x4 z = {0.f, 0.f, 0.f, 0.f};
        acc[g] = z;
    }

    for (int kt = 0; kt < 8; ++kt) {
        __syncthreads();
        stage16(gA0 + kt * 128, sA + w * 1024);
        stage16(gA1 + kt * 128, sA + 4096 + w * 1024);
        const char* Bkt = BbL + kt * 12288 + w * 1024;
        stage16(Bkt,        sB + w * 1024);
        stage16(Bkt + 4096, sB + 4096 + w * 1024);
        stage16(Bkt + 8192, sB + 8192 + w * 1024);
        asm volatile("s_waitcnt vmcnt(0)" ::: "memory");
        __syncthreads();
        f16x8 a0 = *(const f16x8*)(sA + offA0);
        f16x8 a1 = *(const f16x8*)(sA + offA1);
#pragma unroll
        for (int g = 0; g < 6; ++g) {
            f16x8 b0 = *(const f16x8*)(sB + offB[g][0]);
            acc[g] = __builtin_amdgcn_mfma_f32_16x16x32_f16(a0, b0, acc[g], 0, 0, 0);
            f16x8 b1 = *(const f16x8*)(sB + offB[g][1]);
            acc[g] = __builtin_amdgcn_mfma_f32_16x16x32_f16(a1, b1, acc[g], 0, 0, 0);
        }
    }

    const float* bi = gru ? bih_t : bih_s;
    const float* bh = gru ? bhh_t : bhh_s;
    const _Float16* gib = gi_step + (size_t)gru * N_ * 1536;
    int row_l = w * 16 + qq * 4;
#pragma unroll
    for (int jgl = 0; jgl < 2; ++jgl) {
        int j = (Nt * 2 + jgl) * 16 + ml;
        float bir = bi[j], biz = bi[D_ + j], bin = bi[2 * D_ + j];
        float bhr = bh[j], bhz = bh[D_ + j], bhn = bh[2 * D_ + j];
#pragma unroll
        for (int reg = 0; reg < 4; ++reg) {
            int row = Mt * 64 + row_l + reg;
            size_t gb = (size_t)row * 1536 + Nt * 96 + jgl * 48 + ml;
            float gr = (float)gib[gb];
            float gz = (float)gib[gb + 16];
            float gn = (float)gib[gb + 32];
            size_t idx = ((size_t)gru * N_ + row) * D_ + j;
            float r = 1.f / (1.f + __expf(-(acc[jgl * 3 + 0][reg] + gr + bir + bhr)));
            float z = 1.f / (1.f + __expf(-(acc[jgl * 3 + 1][reg] + gz + biz + bhz)));
            float nn = tanhf(gn + bin + r * (acc[jgl * 3 + 2][reg] + bhn));
            float hp = (float)hbf_in[idx];
            float hv = (1.f - z) * nn + z * hp;
            hbf_out[idx] = (_Float16)hv;
        }
    }
}

// ---------------------------------------------------------------------------
__global__ __launch_bounds__(256) void head_kernel(
    const _Float16* __restrict__ hs2, const _Float16* __restrict__ ht2,
    const float* __restrict__ Wps, const float* __restrict__ bps,
    const float* __restrict__ Wpt, const float* __restrict__ bpt,
    const float* __restrict__ x, float* __restrict__ out) {
    int g = blockIdx.x * 256 + threadIdx.x;
    int n = g >> 4, p = g & 15;
    int b = n >> 5, c = n & 31;
    const _Float16* hs = hs2 + (size_t)n * D_;
    const _Float16* ht = ht2 + (size_t)n * D_;
    const float* ws = Wps + (size_t)p * D_;
    const float* wt = Wpt + (size_t)p * D_;
    float acc = bps[p] + bpt[p];
    for (int k = 0; k < D_; ++k)
        acc += (float)hs[k] * ws[k] + (float)ht[k] * wt[k];
    float last = x[((size_t)b * L_ + (L_ - 1)) * C_ + c];
    out[((size_t)b * SEG_ + p) * C_ + c] = acc + last;
}

// ---------------------------------------------------------------------------
extern "C" void kernel_launch(void* const* d_in, const int* in_sizes, int n_in,
                              void* d_out, int out_size, void* d_ws, size_t ws_size,
                              hipStream_t stream) {
    const float* x     = (const float*)d_in[0];
    const float* W_emb = (const float*)d_in[1];
    const float* b_emb = (const float*)d_in[2];
    const float* Wih_s = (const float*)d_in[3];
    const float* Whh_s = (const float*)d_in[4];
    const float* bih_s = (const float*)d_in[5];
    const float* bhh_s = (const float*)d_in[6];
    const float* Wih_t = (const float*)d_in[7];
    const float* Whh_t = (const float*)d_in[8];
    const float* bih_t = (const float*)d_in[9];
    const float* bhh_t = (const float*)d_in[10];
    const float* pos_s = (const float*)d_in[11];
    const float* ch_s  = (const float*)d_in[12];
    const float* pos_t = (const float*)d_in[13];
    const float* ch_t  = (const float*)d_in[14];
    const float* Wps   = (const float*)d_in[15];
    const float* bps   = (const float*)d_in[16];
    const float* Wpt   = (const float*)d_in[17];
    const float* bpt   = (const float*)d_in[18];
    float* out = (float*)d_out;

    char* p = (char*)d_ws;
    float* xs_seg = (float*)p;          p += (size_t)SX_ * N_ * SEG_ * 4;       // 4 MB
    float* xt_seg = (float*)p;          p += (size_t)SX_ * N_ * SEG_ * 4;       // 4 MB
    _Float16* emb_buf = (_Float16*)p;   p += (size_t)16 * 2 * N_ * D_ * 2;      // 32 MB
    _Float16* gi_buf  = (_Float16*)p;   p += (size_t)16 * 2 * N_ * 1536 * 2;    // 96 MB
    _Float16* gi_pe   = (_Float16*)p;   p += (size_t)2 * N_ * 1536 * 2;         // 6 MB
    _Float16* pe_buf  = (_Float16*)p;   p += (size_t)2 * N_ * D_ * 2;           // 2 MB
    _Float16* wih_pk  = (_Float16*)p;   p += (size_t)2 * 16 * 1536 * 32 * 2;    // 3 MB
    _Float16* whh_pk3 = (_Float16*)p;   p += (size_t)2 * 16 * 8 * 768 * 8 * 2;  // 3 MB
    _Float16* hbf0 = (_Float16*)p;      p += (size_t)2 * N_ * D_ * 2;           // 2 MB
    _Float16* hbf1 = (_Float16*)p;      p += (size_t)2 * N_ * D_ * 2;           // 2 MB

    hipMemsetAsync(hbf0, 0, (size_t)2 * N_ * D_ * 2, stream);

    pack_wih_kernel<<<6144, 256, 0, stream>>>(Wih_s, Wih_t, wih_pk);
    pack_whh3_kernel<<<6144, 256, 0, stream>>>(Whh_s, Whh_t, whh_pk3);
    pack_pe_kernel<<<4096, 256, 0, stream>>>(pos_s, ch_s, pos_t, ch_t, pe_buf);
    prep_kernel<<<B_ * 4, 256, 0, stream>>>(x, xs_seg, xt_seg);

    dim3 sgrid(16, 16, 2);
    for (int b = 0; b < 4; ++b) {
        emb_kernel<<<512, 256, 0, stream>>>(xs_seg, xt_seg, W_emb, b_emb, emb_buf, b * 16);
        gi_gemm_kernel<<<dim3(48, 16, 2), 512, 0, stream>>>(
            emb_buf, pe_buf, wih_pk, gi_buf, gi_pe, 0);
        for (int sl = 0; sl < 16; ++sl) {
            int it = b * 16 + sl;
            const _Float16* hbin = (it & 1) ? hbf1 : hbf0;
            _Float16* hbout      = (it & 1) ? hbf0 : hbf1;
            gru_step_mfma<<<sgrid, 256, 0, stream>>>(
                whh_pk3, gi_buf + (size_t)sl * 2 * N_ * 1536,
                bih_s, bhh_s, bih_t, bhh_t, hbin, hbout);
        }
    }
    // decoder: gi from pe; state in *0 -> write *1
    gi_gemm_kernel<<<dim3(48, 1, 2), 512, 0, stream>>>(
        emb_buf, pe_buf, wih_pk, gi_buf, gi_pe, 1);
    gru_step_mfma<<<sgrid, 256, 0, stream>>>(
        whh_pk3, gi_pe, bih_s, bhh_s, bih_t, bhh_t, hbf0, hbf1);

    head_kernel<<<N_ * SEG_ / 256, 256, 0, stream>>>(
        hbf1, hbf1 + (size_t)N_ * D_, Wps, bps, Wpt, bpt, x, out);
}